// Round 1
// baseline (146.946 us; speedup 1.0000x reference)
//
#include <hip/hip_runtime.h>
#include <hip/hip_bf16.h>

#define BATCH 256
#define NQ 1000
#define NC 80
#define QC 80000      // NQ*NC
#define KTOP 300
#define NT 1024
#define NBINS 4096
#define CAP 1024

// order-preserving map f32 -> u32 (monotone: larger float -> larger uint)
__device__ __forceinline__ unsigned mono_key(float x) {
    unsigned u = __float_as_uint(x);
    return (u & 0x80000000u) ? ~u : (u | 0x80000000u);
}
__device__ __forceinline__ float inv_key(unsigned k) {
    unsigned u = (k & 0x80000000u) ? (k & 0x7FFFFFFFu) : ~k;
    return __uint_as_float(u);
}

// Bit-exact replica of XLA's logistic: 0.5 + 0.5*tanh(0.5*x),
// tanh = Eigen/XLA fast-tanh f32 rational with FMA Horner.
__device__ __forceinline__ float ref_sigmoid(float x) {
    float in = __fmul_rn(0.5f, x);                       // exact (pow2 scale)
    float xc = fminf(fmaxf(in, -7.90531110763549805f), 7.90531110763549805f);
    float x2 = __fmul_rn(xc, xc);
    float p = fmaf(x2, -2.76076847742355e-16f, 2.00018790482477e-13f); // a13,a11
    p = fmaf(x2, p, -8.60467152213735e-11f);  // a9
    p = fmaf(x2, p,  5.12229709037114e-08f);  // a7
    p = fmaf(x2, p,  1.48572235717979e-05f);  // a5
    p = fmaf(x2, p,  6.37261928875436e-04f);  // a3
    p = fmaf(x2, p,  4.89352455891786e-03f);  // a1
    float num = __fmul_rn(xc, p);
    float den = fmaf(x2, 1.19825839466702e-06f, 1.18534705686654e-04f); // b6,b4
    den = fmaf(x2, den, 2.26843463243900e-03f);  // b2
    den = fmaf(x2, den, 4.89352518554385e-03f);  // b0
    float t = num / den;                          // IEEE div, correctly rounded
    t = (fabsf(in) < 0.0004f) ? in : t;           // tiny-input passthrough
    return __fadd_rn(0.5f, __fmul_rn(0.5f, t));   // 0.5*t exact, one rounding
}

__global__ __launch_bounds__(NT)
void rtdetr_post_kernel(const float* __restrict__ logits,
                        const float* __restrict__ boxes,
                        const float* __restrict__ sizes,
                        float* __restrict__ out) {
    __shared__ unsigned hist[NBINS];
    __shared__ unsigned long long cand[CAP];
    __shared__ unsigned scan[NT];
    __shared__ unsigned s_tbin, s_count;

    const int b = blockIdx.x;
    const int tid = threadIdx.x;
    const float4* lg4 = (const float4*)(logits + (size_t)b * QC);

    for (int i = tid; i < NBINS; i += NT) hist[i] = 0;
    if (tid == 0) s_count = 0;
    __syncthreads();

    // ---- pass 1: 12-bit histogram of monotone logit keys (float4 loads) ----
    for (int i = tid; i < QC / 4; i += NT) {
        float4 v = lg4[i];
        atomicAdd(&hist[mono_key(v.x) >> 20], 1u);
        atomicAdd(&hist[mono_key(v.y) >> 20], 1u);
        atomicAdd(&hist[mono_key(v.z) >> 20], 1u);
        atomicAdd(&hist[mono_key(v.w) >> 20], 1u);
    }
    __syncthreads();

    // ---- find bin containing rank KTOP (descending) via suffix scan ----
    unsigned h0 = hist[tid * 4 + 0], h1 = hist[tid * 4 + 1];
    unsigned h2 = hist[tid * 4 + 2], h3 = hist[tid * 4 + 3];
    scan[tid] = h0 + h1 + h2 + h3;
    __syncthreads();
    for (int off = 1; off < NT; off <<= 1) {
        unsigned v = (tid + off < NT) ? scan[tid + off] : 0u;
        __syncthreads();
        scan[tid] += v;
        __syncthreads();
    }
    unsigned run = (tid + 1 < NT) ? scan[tid + 1] : 0u;  // count in bins above this thread's
    unsigned hs[4] = {h3, h2, h1, h0};
    #pragma unroll
    for (int j = 0; j < 4; ++j) {
        unsigned bin = (unsigned)(tid * 4 + (3 - j));
        if (run < KTOP && KTOP <= run + hs[j]) s_tbin = bin;  // unique writer
        run += hs[j];
    }
    __syncthreads();

    unsigned thresh = s_tbin << 20;
    thresh = (thresh >= 4096u) ? thresh - 4096u : 0u;  // margin: covers sigmoid-rounding ties

    // ---- pass 2: collect candidates >= thresh, key = (sigmoid_key, ~idx) ----
    for (int i = tid; i < QC / 4; i += NT) {
        float4 v = lg4[i];
        float xs[4] = {v.x, v.y, v.z, v.w};
        #pragma unroll
        for (int j = 0; j < 4; ++j) {
            if (mono_key(xs[j]) >= thresh) {
                unsigned pos = atomicAdd(&s_count, 1u);
                if (pos < CAP) {
                    unsigned sk = mono_key(ref_sigmoid(xs[j]));
                    unsigned idx = (unsigned)(i * 4 + j);
                    cand[pos] = ((unsigned long long)sk << 32) | (unsigned)(~idx);
                }
            }
        }
    }
    __syncthreads();
    unsigned cnt = s_count; if (cnt > CAP) cnt = CAP;
    for (int i = tid; i < CAP; i += NT) if ((unsigned)i >= cnt) cand[i] = 0ull;
    __syncthreads();

    // ---- bitonic sort CAP entries, descending (ties: larger ~idx = lower idx first) ----
    for (int sz = 2; sz <= CAP; sz <<= 1) {
        for (int st = sz >> 1; st > 0; st >>= 1) {
            int i = tid;
            int ixj = i ^ st;
            if (ixj > i) {
                bool desc = ((i & sz) == 0);
                unsigned long long a = cand[i], c = cand[ixj];
                bool sw = desc ? (a < c) : (a > c);
                if (sw) { cand[i] = c; cand[ixj] = a; }
            }
            __syncthreads();
        }
    }

    // ---- emit top 300: labels | boxes(xyxy*WH) | scores ----
    if (tid < KTOP) {
        unsigned long long cd = cand[tid];
        unsigned sk = (unsigned)(cd >> 32);
        unsigned idx = ~((unsigned)cd);
        float score = inv_key(sk);
        unsigned label = idx % NC;
        unsigned qi = idx / NC;
        float4 bx = ((const float4*)boxes)[(size_t)b * NQ + qi];
        float W = sizes[b * 2 + 0];
        float H = sizes[b * 2 + 1];
        float x0 = (bx.x - 0.5f * bx.z) * W;
        float y0 = (bx.y - 0.5f * bx.w) * H;
        float x1 = (bx.x + 0.5f * bx.z) * W;
        float y1 = (bx.y + 0.5f * bx.w) * H;
        int o = b * KTOP + tid;
        out[o] = (float)label;
        float* ob = out + BATCH * KTOP;
        ob[(size_t)o * 4 + 0] = x0;
        ob[(size_t)o * 4 + 1] = y0;
        ob[(size_t)o * 4 + 2] = x1;
        ob[(size_t)o * 4 + 3] = y1;
        float* os = out + BATCH * KTOP * 5;
        os[o] = score;
    }
}

extern "C" void kernel_launch(void* const* d_in, const int* in_sizes, int n_in,
                              void* d_out, int out_size, void* d_ws, size_t ws_size,
                              hipStream_t stream) {
    const float* logits = (const float*)d_in[0];
    const float* boxes  = (const float*)d_in[1];
    const float* sizes  = (const float*)d_in[2];
    float* out = (float*)d_out;
    rtdetr_post_kernel<<<BATCH, NT, 0, stream>>>(logits, boxes, sizes, out);
}

// Round 3
// 128.703 us; speedup vs baseline: 1.1417x; 1.1417x over previous
//
#include <hip/hip_runtime.h>
#include <hip/hip_bf16.h>

#define BATCH 256
#define NQ 1000
#define NC 80
#define QC 80000      // NQ*NC
#define KTOP 300
#define NT 1024
#define NBINS 4096
#define CAP 1024
#define T0 2.55f      // static pre-threshold: ~431 exp. candidates/batch, >=300 at -6.3 sigma

// order-preserving map f32 -> u32 (monotone: larger float -> larger uint)
__device__ __forceinline__ unsigned mono_key(float x) {
    unsigned u = __float_as_uint(x);
    return (u & 0x80000000u) ? ~u : (u | 0x80000000u);
}
__device__ __forceinline__ float inv_key(unsigned k) {
    unsigned u = (k & 0x80000000u) ? (k & 0x7FFFFFFFu) : ~k;
    return __uint_as_float(u);
}

// Bit-exact replica of XLA's logistic: 0.5 + 0.5*tanh(0.5*x)  (verified absmax 0.0)
__device__ __forceinline__ float ref_sigmoid(float x) {
    float in = __fmul_rn(0.5f, x);
    float xc = fminf(fmaxf(in, -7.90531110763549805f), 7.90531110763549805f);
    float x2 = __fmul_rn(xc, xc);
    float p = fmaf(x2, -2.76076847742355e-16f, 2.00018790482477e-13f);
    p = fmaf(x2, p, -8.60467152213735e-11f);
    p = fmaf(x2, p,  5.12229709037114e-08f);
    p = fmaf(x2, p,  1.48572235717979e-05f);
    p = fmaf(x2, p,  6.37261928875436e-04f);
    p = fmaf(x2, p,  4.89352455891786e-03f);
    float num = __fmul_rn(xc, p);
    float den = fmaf(x2, 1.19825839466702e-06f, 1.18534705686654e-04f);
    den = fmaf(x2, den, 2.26843463243900e-03f);
    den = fmaf(x2, den, 4.89352518554385e-03f);
    float t = num / den;
    t = (fabsf(in) < 0.0004f) ? in : t;
    return __fadd_rn(0.5f, __fmul_rn(0.5f, t));
}

__global__ __launch_bounds__(NT)
void rtdetr_post_kernel(const float* __restrict__ logits,
                        const float* __restrict__ boxes,
                        const float* __restrict__ sizes,
                        float* __restrict__ out) {
    __shared__ unsigned long long cand[CAP];
    __shared__ unsigned hist[NBINS];     // fallback only
    __shared__ unsigned scan[NT];        // fallback only
    __shared__ unsigned s_tbin, s_count;

    const int b = blockIdx.x;
    const int tid = threadIdx.x;
    const float4* lg4 = (const float4*)(logits + (size_t)b * QC);

    if (tid == 0) s_count = 0;
    __syncthreads();

    // ---- common path: single streaming read, static threshold ----
    for (int i = tid; i < QC / 4; i += NT) {
        float4 v = lg4[i];
        float xs[4] = {v.x, v.y, v.z, v.w};
        #pragma unroll
        for (int j = 0; j < 4; ++j) {
            if (xs[j] >= T0) {
                unsigned pos = atomicAdd(&s_count, 1u);
                if (pos < CAP) {
                    unsigned sk = mono_key(ref_sigmoid(xs[j]));
                    unsigned idx = (unsigned)(i * 4 + j);
                    cand[pos] = ((unsigned long long)sk << 32) | (unsigned)(~idx);
                }
            }
        }
    }
    __syncthreads();
    unsigned cnt = s_count;

    // ---- exact fallback (never taken for this data): histogram-based threshold ----
    if (cnt < KTOP || cnt > CAP) {
        for (int i = tid; i < NBINS; i += NT) hist[i] = 0;
        if (tid == 0) s_count = 0;
        __syncthreads();
        for (int i = tid; i < QC / 4; i += NT) {
            float4 v = lg4[i];
            atomicAdd(&hist[mono_key(v.x) >> 20], 1u);
            atomicAdd(&hist[mono_key(v.y) >> 20], 1u);
            atomicAdd(&hist[mono_key(v.z) >> 20], 1u);
            atomicAdd(&hist[mono_key(v.w) >> 20], 1u);
        }
        __syncthreads();
        unsigned h0 = hist[tid * 4 + 0], h1 = hist[tid * 4 + 1];
        unsigned h2 = hist[tid * 4 + 2], h3 = hist[tid * 4 + 3];
        scan[tid] = h0 + h1 + h2 + h3;
        __syncthreads();
        for (int off = 1; off < NT; off <<= 1) {
            unsigned v = (tid + off < NT) ? scan[tid + off] : 0u;
            __syncthreads();
            scan[tid] += v;
            __syncthreads();
        }
        unsigned run = (tid + 1 < NT) ? scan[tid + 1] : 0u;
        unsigned hs[4] = {h3, h2, h1, h0};
        #pragma unroll
        for (int j = 0; j < 4; ++j) {
            unsigned bin = (unsigned)(tid * 4 + (3 - j));
            if (run < KTOP && KTOP <= run + hs[j]) s_tbin = bin;
            run += hs[j];
        }
        __syncthreads();
        unsigned thresh = s_tbin << 20;
        thresh = (thresh >= 4096u) ? thresh - 4096u : 0u;
        for (int i = tid; i < QC / 4; i += NT) {
            float4 v = lg4[i];
            float xs[4] = {v.x, v.y, v.z, v.w};
            #pragma unroll
            for (int j = 0; j < 4; ++j) {
                if (mono_key(xs[j]) >= thresh) {
                    unsigned pos = atomicAdd(&s_count, 1u);
                    if (pos < CAP) {
                        unsigned sk = mono_key(ref_sigmoid(xs[j]));
                        unsigned idx = (unsigned)(i * 4 + j);
                        cand[pos] = ((unsigned long long)sk << 32) | (unsigned)(~idx);
                    }
                }
            }
        }
        __syncthreads();
        cnt = s_count; if (cnt > CAP) cnt = CAP;
    }

    // ---- rank selection: rank = #keys greater; unique keys -> unique ranks ----
    if (tid < (int)cnt) {
        unsigned long long my = cand[tid];
        unsigned rank = 0;
        for (unsigned j = 0; j < cnt; ++j) rank += (cand[j] > my) ? 1u : 0u;
        if (rank < KTOP) {
            unsigned sk = (unsigned)(my >> 32);
            unsigned idx = ~((unsigned)my);
            float score = inv_key(sk);
            unsigned label = idx % NC;
            unsigned qi = idx / NC;
            float4 bx = ((const float4*)boxes)[(size_t)b * NQ + qi];
            float W = sizes[b * 2 + 0];
            float H = sizes[b * 2 + 1];
            float x0 = (bx.x - 0.5f * bx.z) * W;
            float y0 = (bx.y - 0.5f * bx.w) * H;
            float x1 = (bx.x + 0.5f * bx.z) * W;
            float y1 = (bx.y + 0.5f * bx.w) * H;
            int o = b * KTOP + (int)rank;
            out[o] = (float)label;
            float* ob = out + BATCH * KTOP;
            ob[(size_t)o * 4 + 0] = x0;
            ob[(size_t)o * 4 + 1] = y0;
            ob[(size_t)o * 4 + 2] = x1;
            ob[(size_t)o * 4 + 3] = y1;
            float* os = out + BATCH * KTOP * 5;
            os[o] = score;
        }
    }
}

extern "C" void kernel_launch(void* const* d_in, const int* in_sizes, int n_in,
                              void* d_out, int out_size, void* d_ws, size_t ws_size,
                              hipStream_t stream) {
    const float* logits = (const float*)d_in[0];
    const float* boxes  = (const float*)d_in[1];
    const float* sizes  = (const float*)d_in[2];
    float* out = (float*)d_out;
    rtdetr_post_kernel<<<BATCH, NT, 0, stream>>>(logits, boxes, sizes, out);
}